// Round 16
// baseline (290.715 us; speedup 1.0000x reference)
//
#include <hip/hip_runtime.h>

#define LOG2E 1.442695040888963f

typedef float f32x2 __attribute__((ext_vector_type(2)));
typedef float f32x4 __attribute__((ext_vector_type(4)));

// packed fp32 FMA / MUL (VOP3P; halves dot instruction count)
static __device__ __forceinline__ void pkfma(f32x2& acc, f32x2 a, f32x2 b) {
    asm("v_pk_fma_f32 %0, %1, %2, %0" : "+v"(acc) : "v"(a), "v"(b));
}
static __device__ __forceinline__ void pkmul(f32x2& d, f32x2 a, f32x2 b) {
    asm("v_pk_mul_f32 %0, %1, %2" : "=v"(d) : "v"(a), "v"(b));
}

// One batch element per 64-lane wave (2048 blocks, 2 waves/SIMD).
// Lane mapping (j = l & 31, rows clamped j>=26):
//   lanes  0..25: dot0 = i_j, dot1 = g_j   (produce pr = sig(i)*scaled-tanh(g))
//   lanes 32..57: dot0 = f_j, dot1 = o_j   (hold C', produce h)
// Cross-lane i*g -> c-lane: permlane32_swap(y0, pr), rcv = sw[0] (HW-proven R12).
// Cell state C' = -2*log2e*c; h = fma(rcp(1+exp2(C')), 2*sig(o), -sig(o)).
//
// R16 micro-cuts vs R15 (chain-bound at C~766cy/wave-step; waves overlap
// fully, so only C matters):
//  1. MERGED-RCP pr path: pr = fma(d1,E1,s1+d1) * rcp(fma(E1,u,u)), u=1+E0.
//     Exact algebra; removes one add + one fma from the permlane-feeding
//     chain. Hi lanes' sig(f)/sig(o) via two parallel rcps (issue-only).
//  2. h broadcast as 7x ds_read_b128 (was 13x b64): fewer DS ops, last pair
//     arrives sooner.
//  3. Anti-phase skew deleted (proven neutral R12/R15).
__launch_bounds__(64, 2)
__global__ void lstm_char_kernel(const int* __restrict__ x,      // [B,T] int32
                                 const float* __restrict__ E,     // [26,26]
                                 const float* __restrict__ W_ih,  // [104,26]
                                 const float* __restrict__ W_hh,  // [104,26]
                                 const float* __restrict__ b_ih,  // [104]
                                 const float* __restrict__ b_hh,  // [104]
                                 const float* __restrict__ W_lin, // [26,26]
                                 const float* __restrict__ b_lin, // [26]
                                 float* __restrict__ out,         // [B,26]
                                 int T)
{
    constexpr int H = 26;

    __shared__ __align__(16) f32x2 P[26][64];   // 13312 B, pair-interleaved
    __shared__ __align__(16) float hb[2][32];   // double-buffered h

    const int b = blockIdx.x;
    const int l = threadIdx.x;
    const int j = l & 31;
    const bool lo = (l < 32);
    const int rr = (j < 26) ? j : 0;            // clamp inactive lanes to row 0
    const int r0 = lo ? rr : 26 + rr;           // i or f row
    const int r1 = lo ? 52 + rr : 78 + rr;      // g or o row
    const size_t xbase = (size_t)b * T;

    hb[0][j] = 0.0f;
    hb[1][j] = 0.0f;

    // exp2 prescales: dot0 (i or f) sigmoid; dot1 scaled-tanh (g) or sigmoid (o)
    const float m0 = -LOG2E;
    const float m1 = lo ? (-2.0f * LOG2E) : (-LOG2E);
    const float s1 = lo ? (-4.0f * LOG2E) : 1.0f;
    const float d1 = lo ? ( 2.0f * LOG2E) : 0.0f;
    const float sd1 = s1 + d1;                  // merged-rcp numerator constant

    // ---- prescaled fp32 recurrent weights as packed pairs ----
    f32x2 wh0p[13], wh1p[13];
    #pragma unroll
    for (int k = 0; k < 13; ++k) {
        wh0p[k] = f32x2{W_hh[r0 * H + 2 * k] * m0, W_hh[r0 * H + 2 * k + 1] * m0};
        wh1p[k] = f32x2{W_hh[r1 * H + 2 * k] * m1, W_hh[r1 * H + 2 * k + 1] * m1};
    }

    // ---- build prescaled pair-interleaved P table (E direct from global) ----
    {
        float wi0[H], wi1[H];
        #pragma unroll
        for (int k = 0; k < H; ++k) {
            wi0[k] = W_ih[r0 * H + k];
            wi1[k] = W_ih[r1 * H + k];
        }
        const float bias0 = b_ih[r0] + b_hh[r0];
        const float bias1 = b_ih[r1] + b_hh[r1];
        for (int ch = 0; ch < 26; ++ch) {
            float a0 = bias0, a1 = bias1;
            #pragma unroll
            for (int k = 0; k < H; ++k) {
                float e = E[ch * H + k];
                a0 = fmaf(wi0[k], e, a0);
                a1 = fmaf(wi1[k], e, a1);
            }
            P[ch][l] = f32x2{a0 * m0, a1 * m1};
        }
    }
    __syncthreads();

    const char* Pb = (const char*)&P[0][0];
    const int lane8 = l << 3;
    const int tm = T - 1;                       // T = 1024 (pow2 mask)
    int hidx = (l - 32) & 63;                   // 32..57 -> 0..25; junk clamped
    hidx = hidx < 32 ? hidx : 31;

    // ---- pipeline prologue ----
    int poffn = (int)x[xbase + 1] * 512;
    f32x2 pa;
    {
        int p0 = (int)x[xbase] * 512;
        pa = *(const f32x2*)(Pb + p0 + lane8);
    }
    float C = 0.0f;                   // C' = -2*log2e*c, lives in lanes 32..57

#define LSTM_STEP(RB, WB, tc)                                                 \
    {                                                                         \
        f32x4 h4[7];                                                          \
        _Pragma("unroll")                                                     \
        for (int q = 0; q < 7; ++q) h4[q] = ((const f32x4*)(RB))[q];          \
        const f32x2* hp = (const f32x2*)h4;                                   \
        f32x2 pn = *(const f32x2*)(Pb + poffn + lane8);                       \
        int poff2 = (int)x[xbase + (((tc) + 2) & tm)] * 512;                  \
        f32x2 A0, A1, B0, B1;                                                 \
        pkmul(A0, hp[0], wh0p[0]);                                            \
        pkmul(A1, hp[1], wh0p[1]);                                            \
        pkmul(B0, hp[0], wh1p[0]);                                            \
        pkmul(B1, hp[1], wh1p[1]);                                            \
        _Pragma("unroll")                                                     \
        for (int k = 2; k < 12; k += 2) {                                     \
            pkfma(A0, hp[k],     wh0p[k]);                                    \
            pkfma(A1, hp[k + 1], wh0p[k + 1]);                                \
            pkfma(B0, hp[k],     wh1p[k]);                                    \
            pkfma(B1, hp[k + 1], wh1p[k + 1]);                                \
        }                                                                     \
        pkfma(A0, hp[12], wh0p[12]);                                          \
        pkfma(B0, hp[12], wh1p[12]);                                          \
        f32x2 sa = A0 + A1;                                                   \
        f32x2 sb = B0 + B1;                                                   \
        const float a0s = sa.x + sa.y + pa.x;                                 \
        const float a1s = sb.x + sb.y + pa.y;                                 \
        float E0 = __builtin_amdgcn_exp2f(a0s);                               \
        float E1 = __builtin_amdgcn_exp2f(a1s);                               \
        float u  = 1.0f + E0;                                                 \
        float w  = 1.0f + E1;                                                 \
        /* merged-rcp pr: sig(i)*scaled_tanh(g) in one rcp (exact algebra) */ \
        float rv = __builtin_amdgcn_rcpf(fmaf(E1, u, u));                     \
        float pr = fmaf(d1, E1, sd1) * rv;                                    \
        float y0 = __builtin_amdgcn_rcpf(u);     /* sig(f) in hi lanes */     \
        float y1 = __builtin_amdgcn_rcpf(w);     /* sig(o) in hi lanes */     \
        auto sw = __builtin_amdgcn_permlane32_swap(__float_as_int(y0),        \
                                                   __float_as_int(pr),        \
                                                   false, false);             \
        float rcv = __int_as_float(sw[0]);                                    \
        C = fmaf(y0, C, rcv);                                                 \
        float rc = __builtin_amdgcn_rcpf(1.0f + __builtin_amdgcn_exp2f(C));   \
        float hv = fmaf(rc, y1 + y1, -y1);                                    \
        (WB)[hidx] = hv;                                                      \
        pa = pn; poffn = poff2;                                               \
    }

    for (int t = 0; t < T; t += 2) {
        LSTM_STEP(hb[0], hb[1], t);       // read buf0, write buf1
        LSTM_STEP(hb[1], hb[0], t + 1);   // read buf1, write buf0
    }
#undef LSTM_STEP

    __syncthreads();

    // ---- final linear (T even => last write went to hb[0]) ----
    if (l < H) {
        float acc = b_lin[l];
        #pragma unroll
        for (int k = 0; k < H; ++k)
            acc = fmaf(W_lin[l * H + k], hb[0][k], acc);
        out[(size_t)b * H + l] = acc;
    }
}

extern "C" void kernel_launch(void* const* d_in, const int* in_sizes, int n_in,
                              void* d_out, int out_size, void* d_ws, size_t ws_size,
                              hipStream_t stream) {
    const int*   x     = (const int*)d_in[0];
    const float* E     = (const float*)d_in[1];
    const float* W_ih  = (const float*)d_in[2];
    const float* W_hh  = (const float*)d_in[3];
    const float* b_ih  = (const float*)d_in[4];
    const float* b_hh  = (const float*)d_in[5];
    const float* W_lin = (const float*)d_in[6];
    const float* b_lin = (const float*)d_in[7];
    float* out = (float*)d_out;

    const int T = 1024;
    const int B = in_sizes[0] / T;   // 2048

    lstm_char_kernel<<<B, 64, 0, stream>>>(x, E, W_ih, W_hh, b_ih, b_hh,
                                           W_lin, b_lin, out, T);
}

// Round 17
// 274.783 us; speedup vs baseline: 1.0580x; 1.0580x over previous
//
#include <hip/hip_runtime.h>

#define LOG2E 1.442695040888963f

typedef float f32x2 __attribute__((ext_vector_type(2)));

// packed fp32 FMA / MUL (VOP3P; halves dot instruction count)
static __device__ __forceinline__ void pkfma(f32x2& acc, f32x2 a, f32x2 b) {
    asm("v_pk_fma_f32 %0, %1, %2, %0" : "+v"(acc) : "v"(a), "v"(b));
}
static __device__ __forceinline__ void pkmul(f32x2& d, f32x2 a, f32x2 b) {
    asm("v_pk_mul_f32 %0, %1, %2" : "=v"(d) : "v"(a), "v"(b));
}

// ===== R17 = exact revert to R15, the best-measured variant (275 us). =====
// R16's merged-rcp SERIALIZED the activation tail (rcp waits on both exp2s +
// an extra fma) and regressed 275->291; the parallel-rcp form below is the
// proven-fastest shape.
//
// One batch element per 64-lane wave (2048 blocks, 2 waves/SIMD).
// Lane mapping (j = l & 31, rows clamped j>=26):
//   lanes  0..25: dot0 = i_j (sigmoid), dot1 = g_j (scaled tanh)
//   lanes 32..57: dot0 = f_j (sigmoid), dot1 = o_j (sigmoid)
// Cross-lane i*g -> c-lane: permlane32_swap(y0, pr), rcv = sw[0] (HW-proven R12).
// Cell state C' = -2*log2e*c; h = fma(rcp(1+exp2(C')), 2*sig(o), -sig(o)).
// h double-buffered in LDS (read bufA / write bufB alternating, compile-time
// selection); x read direct from global (wave-uniform s_load, 2-step slack).
//
// Measured model (R5..R16): per-wave serial chain C ~= 766 cy/step is the
// wall; issue 2I ~= 520 < C; transports: LDS 766 < readlane 914 < bpermute
// 1000; occupancy capped by B (2048 waves / 1024 SIMDs). Latency-bound
// structural floor for fp32 at this mapping.
__launch_bounds__(64, 2)
__global__ void lstm_char_kernel(const int* __restrict__ x,      // [B,T] int32
                                 const float* __restrict__ E,     // [26,26]
                                 const float* __restrict__ W_ih,  // [104,26]
                                 const float* __restrict__ W_hh,  // [104,26]
                                 const float* __restrict__ b_ih,  // [104]
                                 const float* __restrict__ b_hh,  // [104]
                                 const float* __restrict__ W_lin, // [26,26]
                                 const float* __restrict__ b_lin, // [26]
                                 float* __restrict__ out,         // [B,26]
                                 int T)
{
    constexpr int H = 26;

    __shared__ __align__(16) f32x2 P[26][64];   // 13312 B, pair-interleaved
    __shared__ __align__(16) float hb[2][32];   // double-buffered h

    const int b = blockIdx.x;
    const int l = threadIdx.x;
    const int j = l & 31;
    const bool lo = (l < 32);
    const int rr = (j < 26) ? j : 0;            // clamp inactive lanes to row 0
    const int r0 = lo ? rr : 26 + rr;           // i or f row
    const int r1 = lo ? 52 + rr : 78 + rr;      // g or o row
    const size_t xbase = (size_t)b * T;

    hb[0][j] = 0.0f;
    hb[1][j] = 0.0f;

    // exp2 prescales: dot0 (i or f) sigmoid; dot1 scaled-tanh (g) or sigmoid (o)
    const float m0 = -LOG2E;
    const float m1 = lo ? (-2.0f * LOG2E) : (-LOG2E);
    const float s1 = lo ? (-4.0f * LOG2E) : 1.0f;   // y1 = fma(rcp, s1, d1)
    const float d1 = lo ? ( 2.0f * LOG2E) : 0.0f;

    // ---- prescaled fp32 recurrent weights as packed pairs ----
    f32x2 wh0p[13], wh1p[13];
    #pragma unroll
    for (int k = 0; k < 13; ++k) {
        wh0p[k] = f32x2{W_hh[r0 * H + 2 * k] * m0, W_hh[r0 * H + 2 * k + 1] * m0};
        wh1p[k] = f32x2{W_hh[r1 * H + 2 * k] * m1, W_hh[r1 * H + 2 * k + 1] * m1};
    }

    // ---- build prescaled pair-interleaved P table (E direct from global) ----
    {
        float wi0[H], wi1[H];
        #pragma unroll
        for (int k = 0; k < H; ++k) {
            wi0[k] = W_ih[r0 * H + k];
            wi1[k] = W_ih[r1 * H + k];
        }
        const float bias0 = b_ih[r0] + b_hh[r0];
        const float bias1 = b_ih[r1] + b_hh[r1];
        for (int ch = 0; ch < 26; ++ch) {
            float a0 = bias0, a1 = bias1;
            #pragma unroll
            for (int k = 0; k < H; ++k) {
                float e = E[ch * H + k];
                a0 = fmaf(wi0[k], e, a0);
                a1 = fmaf(wi1[k], e, a1);
            }
            P[ch][l] = f32x2{a0 * m0, a1 * m1};
        }
    }
    __syncthreads();

    const char* Pb = (const char*)&P[0][0];
    const int lane8 = l << 3;
    const int tm = T - 1;                       // T = 1024 (pow2 mask)
    // write slot: lanes 32..57 -> 0..25 (real h); junk lanes clamped into
    // slots 26..31 (collisions only among junk, never read).
    int hidx = (l - 32) & 63;
    hidx = hidx < 32 ? hidx : 31;

    // ---- pipeline prologue ----
    int poffn = (int)x[xbase + 1] * 512;
    f32x2 pa;
    {
        int p0 = (int)x[xbase] * 512;
        pa = *(const f32x2*)(Pb + p0 + lane8);
    }
    float C = 0.0f;                   // C' = -2*log2e*c, lives in lanes 32..57

#define LSTM_STEP(RB, WB, tc)                                                 \
    {                                                                         \
        f32x2 hp[13];                                                         \
        _Pragma("unroll")                                                     \
        for (int q = 0; q < 13; ++q) hp[q] = ((const f32x2*)(RB))[q];         \
        f32x2 pn = *(const f32x2*)(Pb + poffn + lane8);                       \
        int poff2 = (int)x[xbase + (((tc) + 2) & tm)] * 512;                  \
        f32x2 A0, A1, B0, B1;                                                 \
        pkmul(A0, hp[0], wh0p[0]);                                            \
        pkmul(A1, hp[1], wh0p[1]);                                            \
        pkmul(B0, hp[0], wh1p[0]);                                            \
        pkmul(B1, hp[1], wh1p[1]);                                            \
        _Pragma("unroll")                                                     \
        for (int k = 2; k < 12; k += 2) {                                     \
            pkfma(A0, hp[k],     wh0p[k]);                                    \
            pkfma(A1, hp[k + 1], wh0p[k + 1]);                                \
            pkfma(B0, hp[k],     wh1p[k]);                                    \
            pkfma(B1, hp[k + 1], wh1p[k + 1]);                                \
        }                                                                     \
        pkfma(A0, hp[12], wh0p[12]);                                          \
        pkfma(B0, hp[12], wh1p[12]);                                          \
        f32x2 sa = A0 + A1;                                                   \
        f32x2 sb = B0 + B1;                                                   \
        const float a0s = sa.x + sa.y + pa.x;                                 \
        const float a1s = sb.x + sb.y + pa.y;                                 \
        float y0 = __builtin_amdgcn_rcpf(1.0f + __builtin_amdgcn_exp2f(a0s)); \
        float y1 = fmaf(__builtin_amdgcn_rcpf(                                \
                            1.0f + __builtin_amdgcn_exp2f(a1s)), s1, d1);     \
        float y1_2 = y1 + y1;                                                 \
        float pr = y0 * y1;                                                   \
        auto sw = __builtin_amdgcn_permlane32_swap(__float_as_int(y0),        \
                                                   __float_as_int(pr),        \
                                                   false, false);             \
        float rcv = __int_as_float(sw[0]);                                    \
        C = fmaf(y0, C, rcv);                                                 \
        float rc = __builtin_amdgcn_rcpf(1.0f + __builtin_amdgcn_exp2f(C));   \
        float hv = fmaf(rc, y1_2, -y1);                                       \
        (WB)[hidx] = hv;                                                      \
        pa = pn; poffn = poff2;                                               \
    }

    for (int t = 0; t < T; t += 2) {
        LSTM_STEP(hb[0], hb[1], t);       // read buf0, write buf1
        LSTM_STEP(hb[1], hb[0], t + 1);   // read buf1, write buf0
    }
#undef LSTM_STEP

    __syncthreads();

    // ---- final linear (T even => last write went to hb[0]) ----
    if (l < H) {
        float acc = b_lin[l];
        #pragma unroll
        for (int k = 0; k < H; ++k)
            acc = fmaf(W_lin[l * H + k], hb[0][k], acc);
        out[(size_t)b * H + l] = acc;
    }
}

extern "C" void kernel_launch(void* const* d_in, const int* in_sizes, int n_in,
                              void* d_out, int out_size, void* d_ws, size_t ws_size,
                              hipStream_t stream) {
    const int*   x     = (const int*)d_in[0];
    const float* E     = (const float*)d_in[1];
    const float* W_ih  = (const float*)d_in[2];
    const float* W_hh  = (const float*)d_in[3];
    const float* b_ih  = (const float*)d_in[4];
    const float* b_hh  = (const float*)d_in[5];
    const float* W_lin = (const float*)d_in[6];
    const float* b_lin = (const float*)d_in[7];
    float* out = (float*)d_out;

    const int T = 1024;
    const int B = in_sizes[0] / T;   // 2048

    lstm_char_kernel<<<B, 64, 0, stream>>>(x, E, W_ih, W_hh, b_ih, b_hh,
                                           W_lin, b_lin, out, T);
}